// Round 1
// baseline (575.494 us; speedup 1.0000x reference)
//
#include <hip/hip_runtime.h>
#include <math.h>

// Problem constants (from reference): T=512, E=64, H=2*E=128, b derived at launch.
#define TT 512
#define EE 64
#define HH 128

typedef float f32x4 __attribute__((ext_vector_type(4)));

// Kernel 1: rows[d][h] = (gelu_exact(pos[d] @ W1 + b1) @ W2 + b2)[h]
// One block per distance d (512 blocks), 128 threads (one per output column h).
// ~25 MFLOP total, W1/W2 L2-resident after first touch — a few microseconds.
__global__ void rows_kernel(const float* __restrict__ pos,
                            const float* __restrict__ W1,
                            const float* __restrict__ b1,
                            const float* __restrict__ W2,
                            const float* __restrict__ b2,
                            float* __restrict__ rows) {
    const int d = blockIdx.x;
    const int t = threadIdx.x;   // 0..127

    __shared__ float p[EE];   // pos_table row d
    __shared__ float h[HH];   // hidden activations

    if (t < EE) p[t] = pos[d * EE + t];
    __syncthreads();

    // h[t] = gelu(pos[d] . W1[:,t] + b1[t]), exact gelu (erf form)
    float acc = b1[t];
#pragma unroll
    for (int e = 0; e < EE; ++e) acc += p[e] * W1[e * HH + t];
    h[t] = 0.5f * acc * (1.0f + erff(acc * 0.7071067811865475f));
    __syncthreads();

    // rows[d][t] = h . W2[:,t] + b2[t]
    float acc2 = b2[t];
#pragma unroll
    for (int k = 0; k < HH; ++k) acc2 += h[k] * W2[k * HH + t];
    rows[d * HH + t] = acc2;
}

// Kernel 2: out[b][i][j][:] = rows[max(i-j,0)][:]
// One GROUP = 16 floats = 64 B per thread per iteration (4x float4).
// A row (128 floats) = 8 groups, so 8 consecutive lanes cover one output row;
// a wave writes 4 KB contiguous. Reads come from the 256 KB rows table
// (L1/L2-hot); writes are nontemporal so the 256 MiB stream doesn't evict it.
__global__ void scatter_kernel(const f32x4* __restrict__ rows4,
                               f32x4* __restrict__ out4,
                               long ngroups) {
    const long stride = (long)gridDim.x * blockDim.x;
    for (long g = (long)blockIdx.x * blockDim.x + threadIdx.x; g < ngroups;
         g += stride) {
        const int  qq = (int)(g & 7);            // group within row (128/16 = 8)
        const long r  = g >> 3;                  // flat (b,i,j) row index
        const int  j  = (int)(r & (TT - 1));
        const int  i  = (int)((r >> 9) & (TT - 1));
        const int  d  = (i >= j) ? (i - j) : 0;  // tril(i-j)

        const f32x4* __restrict__ src = rows4 + ((long)d * (HH / 4) + qq * 4);
        const f32x4 v0 = src[0];
        const f32x4 v1 = src[1];
        const f32x4 v2 = src[2];
        const f32x4 v3 = src[3];

        f32x4* dst = out4 + (g << 2);
        __builtin_nontemporal_store(v0, dst + 0);
        __builtin_nontemporal_store(v1, dst + 1);
        __builtin_nontemporal_store(v2, dst + 2);
        __builtin_nontemporal_store(v3, dst + 3);
    }
}

extern "C" void kernel_launch(void* const* d_in, const int* in_sizes, int n_in,
                              void* d_out, int out_size, void* d_ws, size_t ws_size,
                              hipStream_t stream) {
    // setup_inputs order: b(int scalar), pos_table, W1, b1, W2, b2 — all fp32
    const float* pos = (const float*)d_in[1];
    const float* W1  = (const float*)d_in[2];
    const float* b1  = (const float*)d_in[3];
    const float* W2  = (const float*)d_in[4];
    const float* b2  = (const float*)d_in[5];
    float* out  = (float*)d_out;
    float* rows = (float*)d_ws;              // TT*HH*4 = 256 KB scratch

    rows_kernel<<<TT, HH, 0, stream>>>(pos, W1, b1, W2, b2, rows);

    // --- Size-unit detection (the core fix) ---------------------------------
    // pos_table is [512,64] fp32: 131072 bytes / 32768 elements. Whichever
    // in_sizes[1] reports tells us the convention for out_size too.
    // Previous version assumed out_size was a float count; if the harness
    // passes BYTES, it launched 4x the threads and wrote 1 GiB instead of
    // 256 MiB (~160 us of pure waste, corroborated by the 1 GiB poison fills).
    const bool sizes_in_bytes = (in_sizes[1] == TT * EE * 4);
    const long total_floats   = sizes_in_bytes ? (long)out_size / 4
                                               : (long)out_size;
    const long ngroups = total_floats / 16;  // 16 floats per group

    const int  block  = 256;
    long       blocks = (ngroups + block - 1) / block;
    if (blocks > 2048) blocks = 2048;        // grid-stride the rest (G11)

    scatter_kernel<<<dim3((unsigned)blocks), dim3(block), 0, stream>>>(
        (const f32x4*)rows, (f32x4*)out, ngroups);
}

// Round 2
// 264.036 us; speedup vs baseline: 2.1796x; 2.1796x over previous
//
#include <hip/hip_runtime.h>
#include <math.h>

// Problem constants (from reference): T=512, E=64, H=2*E=128, b derived at launch.
#define TT 512
#define EE 64
#define HH 128

// Kernel 1: rows[d][h] = (gelu_exact(pos[d] @ W1 + b1) @ W2 + b2)[h]
// One block per distance d (512 blocks), 512 threads: column c = t&127,
// K-slice s = t>>7 (4-way split of the reduction). Round-0's 128-thread
// version was latency-bound (1 wave/SIMD, 192 serial L2 loads/thread);
// this gives 4x the waves and 1/4 the per-thread load chain.
__global__ __launch_bounds__(512) void rows_kernel(
        const float* __restrict__ pos,
        const float* __restrict__ W1,
        const float* __restrict__ b1,
        const float* __restrict__ W2,
        const float* __restrict__ b2,
        float* __restrict__ rows) {
    const int d = blockIdx.x;
    const int t = threadIdx.x;      // 0..511
    const int c = t & (HH - 1);     // output column 0..127
    const int s = t >> 7;           // K-slice 0..3 (wave-uniform)

    __shared__ float p[EE];         // pos_table row d
    __shared__ float part[4][HH];   // K-slice partial sums
    __shared__ float h[HH];         // hidden activations

    if (t < EE) p[t] = pos[d * EE + t];
    __syncthreads();

    // Phase 1: h = gelu(pos[d] @ W1 + b1); each s-slice sums 16 of 64 terms.
    float acc = (s == 0) ? b1[c] : 0.0f;
    const int e0 = s * (EE / 4);
#pragma unroll
    for (int e = 0; e < EE / 4; ++e)
        acc += p[e0 + e] * W1[(e0 + e) * HH + c];   // coalesced across c
    part[s][c] = acc;
    __syncthreads();

    float hv = part[0][c] + part[1][c] + part[2][c] + part[3][c];
    hv = 0.5f * hv * (1.0f + erff(hv * 0.7071067811865475f));  // exact gelu
    if (s == 0) h[c] = hv;
    __syncthreads();

    // Phase 2: rows[d] = h @ W2 + b2; each s-slice sums 32 of 128 terms.
    float acc2 = (s == 0) ? b2[c] : 0.0f;
    const int k0 = s * (HH / 4);
#pragma unroll
    for (int k = 0; k < HH / 4; ++k)
        acc2 += h[k0 + k] * W2[(k0 + k) * HH + c];  // coalesced across c
    part[s][c] = acc2;
    __syncthreads();

    if (s == 0)
        rows[d * HH + c] = part[0][c] + part[1][c] + part[2][c] + part[3][c];
}

// Kernel 2: out[b][i][j][:] = rows[max(i-j,0)][:]  (round-0 pattern, proven
// 6.2 TB/s). One thread per output float4; consecutive lanes write
// consecutive 16 B -> each wave stores 1 KB contiguous (full lines).
// Reads hit the L2-resident 256 KB rows table (FETCH_SIZE ~0.8 MB measured).
__global__ void scatter_kernel(const float4* __restrict__ rows4,
                               float4* __restrict__ out4) {
    const long idx = (long)blockIdx.x * blockDim.x + threadIdx.x;
    const int  q = (int)(idx & 31);          // float4 index within row (HH/4=32)
    const long r = idx >> 5;                 // flat (b,i,j) row index
    const int  j = (int)(r & (TT - 1));
    const int  i = (int)((r >> 9) & (TT - 1));
    const int  d = (i >= j) ? (i - j) : 0;   // tril(i-j)
    out4[idx] = rows4[d * (HH / 4) + q];
}

extern "C" void kernel_launch(void* const* d_in, const int* in_sizes, int n_in,
                              void* d_out, int out_size, void* d_ws, size_t ws_size,
                              hipStream_t stream) {
    // setup_inputs order: b(int scalar), pos_table, W1, b1, W2, b2 — all fp32
    const float* pos = (const float*)d_in[1];
    const float* W1  = (const float*)d_in[2];
    const float* b1  = (const float*)d_in[3];
    const float* W2  = (const float*)d_in[4];
    const float* b2  = (const float*)d_in[5];
    float* out  = (float*)d_out;
    float* rows = (float*)d_ws;              // TT*HH*4 = 256 KB scratch

    rows_kernel<<<TT, 512, 0, stream>>>(pos, W1, b1, W2, b2, rows);

    // out_size is an ELEMENT count (proven: round-0 wrote out_size/4 float4s
    // and passed verification with full coverage). Keep a byte-units guard
    // anyway — pos_table is 512*64 fp32 = 32768 elements / 131072 bytes.
    const bool sizes_in_bytes = (in_sizes[1] == TT * EE * 4);
    const long total_floats   = sizes_in_bytes ? (long)out_size / 4
                                               : (long)out_size;
    const long total4 = total_floats / 4;
    const int  block  = 256;
    const long grid   = (total4 + block - 1) / block;
    scatter_kernel<<<dim3((unsigned)grid), dim3(block), 0, stream>>>(
        (const float4*)rows, (float4*)out);
}